// Round 1
// baseline (112.232 us; speedup 1.0000x reference)
//
#include <hip/hip_runtime.h>
#include <hip/hip_bf16.h>

typedef unsigned short u16;
typedef __bf16 bf16x8 __attribute__((ext_vector_type(8)));
typedef float f32x4 __attribute__((ext_vector_type(4)));

#define NB 16   // batch
#define NK 32   // K slices
#define ND 256  // D
#define NL 256  // L1 == L2

__device__ __forceinline__ u16 f2bf(float f) {
    __hip_bfloat16 h = __float2bfloat16(f);
    return __builtin_bit_cast(u16, h);
}

// ---------------- prep: f32 -> bf16 straight convert ----------------
__global__ void cvt_kernel(const float* __restrict__ in, u16* __restrict__ out, int n4) {
    int i = blockIdx.x * blockDim.x + threadIdx.x;
    if (i < n4) {
        float4 v = ((const float4*)in)[i];
        ushort4 o;
        o.x = f2bf(v.x); o.y = f2bf(v.y); o.z = f2bf(v.z); o.w = f2bf(v.w);
        ((ushort4*)out)[i] = o;
    }
}

// ---------------- prep: W[k][d][e] f32 -> Wt[k][e][d] bf16 ----------------
__global__ void wt_kernel(const float* __restrict__ W, u16* __restrict__ Wt) {
    long idx = (long)blockIdx.x * 256 + threadIdx.x;    // ((k*ND + e)*ND + d)
    int d = (int)(idx & 255);
    int e = (int)((idx >> 8) & 255);
    int k = (int)(idx >> 16);
    Wt[idx] = f2bf(W[((long)k * ND + d) * ND + e]);
}

// ---------------- prep: lin1[b,k,l] = x1[b,l,:].V1[k] + b[k]; lin2[b,k,m] = x2[b,m,:].V2[k]
__global__ void lin_kernel(const float* __restrict__ x1, const float* __restrict__ x2,
                           const float* __restrict__ V, const float* __restrict__ bb,
                           float* __restrict__ lin1, float* __restrict__ lin2) {
    int bk = blockIdx.x;          // b*NK + k
    int b = bk >> 5, k = bk & 31;
    int t = threadIdx.x;          // row index l (or m)
    const float4* r1 = (const float4*)(x1 + ((long)(b * NL + t)) * ND);
    const float4* r2 = (const float4*)(x2 + ((long)(b * NL + t)) * ND);
    const float4* v1 = (const float4*)(V + (long)k * (2 * ND));
    const float4* v2 = v1 + (ND / 4);
    float s1 = 0.f, s2 = 0.f;
#pragma unroll 8
    for (int i = 0; i < ND / 4; ++i) {
        float4 a = r1[i], w = v1[i];
        s1 += a.x * w.x + a.y * w.y + a.z * w.z + a.w * w.w;
        float4 c = r2[i], u = v2[i];
        s2 += c.x * u.x + c.y * u.y + c.z * u.z + c.w * u.w;
    }
    lin1[(long)bk * NL + t] = s1 + bb[k];
    lin2[(long)bk * NL + t] = s2;
}

// ---------------- main fused kernel ----------------
// grid: 1024 blocks = (b, k, lb) ; 256 threads = 4 waves (2x2 wave grid)
// per block: rows l0..l0+127 (lb half), all 256 cols
// phase A: T[128][256] = x1[b][l0:+128] @ W[k]      (contraction d, B-op from Wt[k][e][d])
// phase B: O[128][256] = T @ x2[b]^T                (contraction e, B-op from x2[b][m][e])
__launch_bounds__(256, 2)
__global__ void ntn_main(const u16* __restrict__ x1bf, const u16* __restrict__ x2bf,
                         const u16* __restrict__ Wt,
                         const float* __restrict__ lin1, const float* __restrict__ lin2,
                         float* __restrict__ out) {
    __shared__ u16 ldsA[128 * 256];   // 64 KiB: x1 block, later aliased by T
    __shared__ u16 ldsS[256 * 32];    // 16 KiB: staging for Wt / x2 tiles (32-wide k-tiles)

    int bid = blockIdx.x;
    int b  = bid >> 6;
    int rem = bid & 63;
    int k  = rem >> 1;
    int lb = rem & 1;
    int l0 = lb * 128;

    int tid = threadIdx.x;
    int lane = tid & 63;
    int wid = tid >> 6;
    int wr = wid >> 1;     // wave row: l-offset wr*64
    int wc = wid & 1;      // wave col: n-offset wc*128

    // ---- stage x1 block (128 rows x 256 cols bf16, 512 B rows), XOR swizzle (row&7)<<4
    {
        const char* src = (const char*)(x1bf + ((long)b * NL + l0) * ND);
#pragma unroll
        for (int it = 0; it < 16; ++it) {
            int chunk = it * 256 + tid;            // 16B chunks, 32 per row
            int row = chunk >> 5;
            int cb  = (chunk & 31) << 4;
            uint4 v = *(const uint4*)(src + row * 512 + cb);
            *(uint4*)((char*)ldsA + row * 512 + (cb ^ ((row & 7) << 4))) = v;
        }
    }
    __syncthreads();

    f32x4 acc[4][8];
    const f32x4 fzero = {0.f, 0.f, 0.f, 0.f};
#pragma unroll
    for (int i = 0; i < 4; ++i)
#pragma unroll
        for (int j = 0; j < 8; ++j) acc[i][j] = fzero;

    // ================= phase A =================
    {
        const char* wsrc = (const char*)(Wt + (long)k * ND * ND);  // [e][d] rows of 512 B
#pragma unroll 1
        for (int dt = 0; dt < 8; ++dt) {
            int d0 = dt * 32;
            // stage Wt[e][d0:d0+32] -> ldsS[e][0:32] (64 B rows), swizzle (row&3)<<4
#pragma unroll
            for (int it = 0; it < 4; ++it) {
                int chunk = it * 256 + tid;        // 4 chunks per row
                int row = chunk >> 2;
                int cb  = (chunk & 3) << 4;
                uint4 v = *(const uint4*)(wsrc + row * 512 + d0 * 2 + cb);
                *(uint4*)((char*)ldsS + row * 64 + (cb ^ ((row & 3) << 4))) = v;
            }
            __syncthreads();

            bf16x8 af[4];
#pragma unroll
            for (int lt = 0; lt < 4; ++lt) {
                int row = wr * 64 + lt * 16 + (lane & 15);
                int cbyte = d0 * 2 + ((lane >> 4) << 4);
                af[lt] = *(const bf16x8*)((const char*)ldsA + row * 512 + (cbyte ^ ((row & 7) << 4)));
            }
#pragma unroll
            for (int nt = 0; nt < 8; ++nt) {
                int row = wc * 128 + nt * 16 + (lane & 15);
                int cbyte = (lane >> 4) << 4;
                bf16x8 bfB = *(const bf16x8*)((const char*)ldsS + row * 64 + (cbyte ^ ((row & 3) << 4)));
#pragma unroll
                for (int lt = 0; lt < 4; ++lt)
                    acc[lt][nt] = __builtin_amdgcn_mfma_f32_16x16x32_bf16(af[lt], bfB, acc[lt][nt], 0, 0, 0);
            }
            __syncthreads();
        }
    }

    // ---- write T (bf16) into ldsA (x1 dead now), same [128][256] swizzled layout
#pragma unroll
    for (int lt = 0; lt < 4; ++lt)
#pragma unroll
        for (int nt = 0; nt < 8; ++nt) {
            int col = wc * 128 + nt * 16 + (lane & 15);
#pragma unroll
            for (int j = 0; j < 4; ++j) {
                int row = wr * 64 + lt * 16 + ((lane >> 4) << 2) + j;
                *(u16*)((char*)ldsA + row * 512 + ((col * 2) ^ ((row & 7) << 4))) = f2bf(acc[lt][nt][j]);
            }
        }
    __syncthreads();

    // ================= phase B =================
#pragma unroll
    for (int i = 0; i < 4; ++i)
#pragma unroll
        for (int j = 0; j < 8; ++j) acc[i][j] = fzero;

    {
        const char* x2src = (const char*)(x2bf + (long)b * NL * ND);   // [m][e] rows of 512 B
#pragma unroll 1
        for (int et = 0; et < 8; ++et) {
            int e0 = et * 32;
#pragma unroll
            for (int it = 0; it < 4; ++it) {
                int chunk = it * 256 + tid;
                int row = chunk >> 2;
                int cb  = (chunk & 3) << 4;
                uint4 v = *(const uint4*)(x2src + row * 512 + e0 * 2 + cb);
                *(uint4*)((char*)ldsS + row * 64 + (cb ^ ((row & 3) << 4))) = v;
            }
            __syncthreads();

            bf16x8 af[4];
#pragma unroll
            for (int lt = 0; lt < 4; ++lt) {
                int row = wr * 64 + lt * 16 + (lane & 15);
                int cbyte = e0 * 2 + ((lane >> 4) << 4);
                af[lt] = *(const bf16x8*)((const char*)ldsA + row * 512 + (cbyte ^ ((row & 7) << 4)));
            }
#pragma unroll
            for (int nt = 0; nt < 8; ++nt) {
                int row = wc * 128 + nt * 16 + (lane & 15);
                int cbyte = (lane >> 4) << 4;
                bf16x8 bfB = *(const bf16x8*)((const char*)ldsS + row * 64 + (cbyte ^ ((row & 3) << 4)));
#pragma unroll
                for (int lt = 0; lt < 4; ++lt)
                    acc[lt][nt] = __builtin_amdgcn_mfma_f32_16x16x32_bf16(af[lt], bfB, acc[lt][nt], 0, 0, 0);
            }
            __syncthreads();
        }
    }

    // ================= epilogue: + lin1 + lin2, relu, store f32 =================
    {
        const float* l1p = lin1 + ((long)(b * NK + k)) * NL + l0;  // includes b[k]
        const float* l2p = lin2 + ((long)(b * NK + k)) * NL;
        float colb[8];
#pragma unroll
        for (int nt = 0; nt < 8; ++nt) colb[nt] = l2p[wc * 128 + nt * 16 + (lane & 15)];
        float* outp = out + (((long)(b * NK + k)) * NL + l0) * NL;
#pragma unroll
        for (int lt = 0; lt < 4; ++lt) {
#pragma unroll
            for (int j = 0; j < 4; ++j) {
                int row = wr * 64 + lt * 16 + ((lane >> 4) << 2) + j;
                float rowb = l1p[row];
#pragma unroll
                for (int nt = 0; nt < 8; ++nt) {
                    float v = acc[lt][nt][j] + rowb + colb[nt];
                    outp[(long)row * NL + wc * 128 + nt * 16 + (lane & 15)] = v > 0.f ? v : 0.f;
                }
            }
        }
    }
}

extern "C" void kernel_launch(void* const* d_in, const int* in_sizes, int n_in,
                              void* d_out, int out_size, void* d_ws, size_t ws_size,
                              hipStream_t stream) {
    const float* x1 = (const float*)d_in[0];
    const float* x2 = (const float*)d_in[1];
    const float* W  = (const float*)d_in[2];
    const float* V  = (const float*)d_in[3];
    const float* bb = (const float*)d_in[4];
    float* out = (float*)d_out;

    char* ws = (char*)d_ws;
    u16*   x1bf = (u16*)(ws);                               // 2 MiB
    u16*   x2bf = (u16*)(ws + (2l << 20));                  // 2 MiB
    u16*   Wt   = (u16*)(ws + (4l << 20));                  // 4 MiB
    float* lin1 = (float*)(ws + (8l << 20));                // 512 KiB
    float* lin2 = (float*)(ws + (8l << 20) + (512l << 10)); // 512 KiB

    hipLaunchKernelGGL(cvt_kernel, dim3(1024), dim3(256), 0, stream, x1, x1bf, (NB * NL * ND) / 4);
    hipLaunchKernelGGL(cvt_kernel, dim3(1024), dim3(256), 0, stream, x2, x2bf, (NB * NL * ND) / 4);
    hipLaunchKernelGGL(wt_kernel, dim3((NK * ND * ND) / 256), dim3(256), 0, stream, W, Wt);
    hipLaunchKernelGGL(lin_kernel, dim3(NB * NK), dim3(256), 0, stream, x1, x2, V, bb, lin1, lin2);
    hipLaunchKernelGGL(ntn_main, dim3(NB * NK * 2), dim3(256), 0, stream, x1bf, x2bf, Wt, lin1, lin2, out);
}